// Round 1
// baseline (244.233 us; speedup 1.0000x reference)
//
#include <hip/hip_runtime.h>
#include <hip/hip_bf16.h>

#define Bdim 64
#define Tdim 2048
#define Fdim 256
#define TAIL 256      // truncated EMA window: 0.8^256 ~ 1e-25, far below fp32 noise
#define NCH 8
#define CHT 32        // TAIL / NCH

#define BM 64
#define BK 64
#define ASTR 72       // padded LDS row stride (ushorts): 144 B, 16B-aligned, breaks pow2 banks
#define BSTR 72

typedef __bf16 bf16x8 __attribute__((ext_vector_type(8)));
typedef float f32x16 __attribute__((ext_vector_type(16)));
typedef unsigned short u16x8 __attribute__((ext_vector_type(8)));

__device__ __forceinline__ unsigned short bf16_rne(float f) {
  unsigned int u = __float_as_uint(f);
  u += 0x7FFFu + ((u >> 16) & 1u);
  return (unsigned short)(u >> 16);
}

// W [f][g] fp32 -> Wt [g][f] bf16 (transposed so GEMM B-fragments are contiguous in k=f)
__global__ void prep_wt(const float* __restrict__ W, unsigned short* __restrict__ Wt) {
  int i = blockIdx.x * 256 + threadIdx.x;   // i = g*256 + f
  int g = i >> 8, f = i & 255;
  Wt[i] = bf16_rne(W[f * Fdim + g]);
}

// partial EMA sums over t-chunks: part[c][b][f]
__global__ void ema_partial(const float* __restrict__ x, float* __restrict__ part) {
  int b = blockIdx.x, c = blockIdx.y, f = threadIdx.x;
  int t0 = Tdim - TAIL + c * CHT;
  // w(t) = 0.2 * 0.8^(T-1-t); iterate upward multiplying by 1.25 (exact in fp32)
  float w = 0.2f * exp2f((float)(Tdim - 1 - t0) * -0.32192809488736235f);
  const float* xp = x + ((size_t)b * Tdim + t0) * Fdim + f;
  float s = 0.f;
#pragma unroll
  for (int j = 0; j < CHT; ++j) {
    s += w * xp[(size_t)j * Fdim];
    w *= 1.25f;
  }
  part[(c * Bdim + b) * Fdim + f] = s;
}

// out[row][n] = sum_k x[row][k]*W[k][n] + bias[n] + lastref[b][n]
// BM=64 rows/block, BN=256 (full, so x is read exactly once), BK=64, 256 thr = 4 waves
__global__ __launch_bounds__(256, 3)
void gemm_fused(const float* __restrict__ x, const unsigned short* __restrict__ Wt,
                const float* __restrict__ bias, const float* __restrict__ part,
                float* __restrict__ out) {
  __shared__ unsigned short Abuf[BM * ASTR];
  __shared__ unsigned short Bbuf[Fdim * BSTR];
  __shared__ float lref[Fdim];

  const int tid = threadIdx.x;
  const int blk = blockIdx.x;            // 0..2047
  const int b = blk >> 5;                // 32 row-tiles per batch (2048/64)
  const size_t row0 = (size_t)blk * BM;  // row in flattened [B*T]

  {  // lastref[b][n] + bias[n], one n per thread
    float s = bias[tid];
#pragma unroll
    for (int c = 0; c < NCH; ++c) s += part[(c * Bdim + b) * Fdim + tid];
    lref[tid] = s;
  }

  const int wave = tid >> 6;   // 0..3 -> n-position (wave covers 64 cols x 64 rows)
  const int lane = tid & 63;
  const int lm = lane & 31;
  const int half = lane >> 5;

  f32x16 acc[2][2] = {};       // [m-subtile][n-subtile], 32x32 each

  const int g8 = (tid & 7) * 8;   // 8-elem granule column
  const int arow = tid >> 3;      // 0..31

  for (int kc = 0; kc < 4; ++kc) {
    const int k0 = kc * BK;
    // stage A: 64x64 fp32 -> bf16.  thread -> (row, 8-col granule); coalesced 32B/lane
#pragma unroll
    for (int p = 0; p < 2; ++p) {
      int r = arow + p * 32;
      const float* src = &x[(row0 + r) * Fdim + k0 + g8];
      float4 v0 = *(const float4*)src;
      float4 v1 = *(const float4*)(src + 4);
      u16x8 w;
      w[0] = bf16_rne(v0.x); w[1] = bf16_rne(v0.y);
      w[2] = bf16_rne(v0.z); w[3] = bf16_rne(v0.w);
      w[4] = bf16_rne(v1.x); w[5] = bf16_rne(v1.y);
      w[6] = bf16_rne(v1.z); w[7] = bf16_rne(v1.w);
      *(u16x8*)&Abuf[r * ASTR + g8] = w;
    }
    // stage B: Wt rows [n][k0..k0+64) bf16, straight copy (L2-resident)
#pragma unroll
    for (int p = 0; p < 8; ++p) {
      int n = arow + p * 32;
      u16x8 wv = *(const u16x8*)&Wt[n * Fdim + k0 + g8];
      *(u16x8*)&Bbuf[n * BSTR + g8] = wv;
    }
    __syncthreads();

    const int ko = half * 8;   // k = 8*(lane/32) + j
#pragma unroll
    for (int s = 0; s < 4; ++s) {
      int kk = s * 16 + ko;
      bf16x8 a0 = *(const bf16x8*)&Abuf[(lm) * ASTR + kk];
      bf16x8 a1 = *(const bf16x8*)&Abuf[(32 + lm) * ASTR + kk];
      bf16x8 b0 = *(const bf16x8*)&Bbuf[(wave * 64 + lm) * BSTR + kk];
      bf16x8 b1 = *(const bf16x8*)&Bbuf[(wave * 64 + 32 + lm) * BSTR + kk];
      acc[0][0] = __builtin_amdgcn_mfma_f32_32x32x16_bf16(a0, b0, acc[0][0], 0, 0, 0);
      acc[0][1] = __builtin_amdgcn_mfma_f32_32x32x16_bf16(a0, b1, acc[0][1], 0, 0, 0);
      acc[1][0] = __builtin_amdgcn_mfma_f32_32x32x16_bf16(a1, b0, acc[1][0], 0, 0, 0);
      acc[1][1] = __builtin_amdgcn_mfma_f32_32x32x16_bf16(a1, b1, acc[1][1], 0, 0, 0);
    }
    __syncthreads();
  }

  // epilogue: C/D layout col=lane&31, row=(r&3)+8*(r>>2)+4*(lane>>5)  [m74/m101]
  float* op = out + row0 * Fdim;
  const int rbase = 4 * half;
#pragma unroll
  for (int i = 0; i < 2; ++i) {
#pragma unroll
    for (int j = 0; j < 2; ++j) {
      int n = wave * 64 + j * 32 + lm;
      float lb = lref[n];
#pragma unroll
      for (int r = 0; r < 16; ++r) {
        int rowi = i * 32 + (r & 3) + 8 * (r >> 2) + rbase;
        op[(size_t)rowi * Fdim + n] = acc[i][j][r] + lb;
      }
    }
  }
}

extern "C" void kernel_launch(void* const* d_in, const int* in_sizes, int n_in,
                              void* d_out, int out_size, void* d_ws, size_t ws_size,
                              hipStream_t stream) {
  const float* x = (const float*)d_in[0];
  const float* W = (const float*)d_in[1];
  const float* bias = (const float*)d_in[2];
  float* out = (float*)d_out;

  unsigned short* Wt = (unsigned short*)d_ws;                       // 128 KB
  float* part = (float*)((char*)d_ws + Fdim * Fdim * sizeof(unsigned short));  // 512 KB

  prep_wt<<<Fdim, 256, 0, stream>>>(W, Wt);
  ema_partial<<<dim3(Bdim, NCH), 256, 0, stream>>>(x, part);
  gemm_fused<<<(Bdim * Tdim) / BM, 256, 0, stream>>>(x, Wt, bias, part, out);
}